// Round 2
// baseline (64.109 us; speedup 1.0000x reference)
//
#include <hip/hip_runtime.h>
#include <hip/hip_bf16.h>

#define NPART 128
#define NBATCH 256
#define NOUT 64
#define NIN 64
#define LDK 72   // padded LDS row stride in bf16 elements (144 B -> max 2-way bank aliasing = free)

typedef __attribute__((ext_vector_type(8))) short short8;        // MFMA A/B frag (8 bf16)
typedef __attribute__((ext_vector_type(4))) float floatx4;       // MFMA C/D frag
typedef __attribute__((ext_vector_type(8))) unsigned short ushort8;

__device__ __forceinline__ unsigned short f_to_bf16(float f) {
    union { unsigned int i; float f; } v; v.f = f;
    unsigned int b = v.i;
    unsigned int r = b + 0x7FFFu + ((b >> 16) & 1u);   // RNE; inputs here are finite positives
    return (unsigned short)(r >> 16);
}

// out[b,p,o] = log( sum_i exp(x[b,p,i]) * exp(w[p,o,i]) ) - log( sum_i exp(w[p,o,i]) )
//            = logsumexp_i( x[b,p,i] + log_softmax(w[p,o,:])[i] )
__global__ __launch_bounds__(256, 2) void sumlayer_kernel(
    const float* __restrict__ x,   // [NBATCH][NPART][NIN] fp32
    const float* __restrict__ w,   // [NPART][NOUT][NIN] fp32
    float* __restrict__ out)       // [NBATCH][NPART][NOUT] fp32
{
    __shared__ alignas(16) unsigned short Alds[64 * LDK];  // bf16(exp(x)) tile
    __shared__ alignas(16) unsigned short Wlds[64 * LDK];  // bf16(exp(w))
    __shared__ float wlse[64];

    const int p  = blockIdx.x;        // partition
    const int b0 = blockIdx.y * 64;   // batch tile origin
    const int t  = threadIdx.x;
    const int row = t >> 2;           // 0..63 (o-row for weights, b-row for x)
    const int sub = t & 3;            // 4 threads per row, 16 elems each

    // ---- stage bf16(exp(weight[p])) -> Wlds, and wlse[o] = log(sum_i exp(w)) in fp32 ----
    {
        const float* wrow = w + (((size_t)p * NOUT + row) * NIN + sub * 16);
        float vals[16];
        #pragma unroll
        for (int j = 0; j < 16; j += 4) {
            float4 v = *(const float4*)(wrow + j);
            vals[j] = v.x; vals[j+1] = v.y; vals[j+2] = v.z; vals[j+3] = v.w;
        }
        float s = 0.f;
        ushort8 e0, e1;
        #pragma unroll
        for (int j = 0; j < 8; ++j) {
            float e = __expf(vals[j]);     s += e; e0[j] = f_to_bf16(e);
        }
        #pragma unroll
        for (int j = 0; j < 8; ++j) {
            float e = __expf(vals[8 + j]); s += e; e1[j] = f_to_bf16(e);
        }
        unsigned short* dst = Wlds + row * LDK + sub * 16;
        *(ushort8*)(dst)     = e0;
        *(ushort8*)(dst + 8) = e1;
        // reduce s across the 4 sub-lanes (adjacent lanes, same wave: rows never straddle a wave)
        s += __shfl_xor(s, 1);
        s += __shfl_xor(s, 2);
        if (sub == 0) wlse[row] = __logf(s);
    }

    // ---- stage bf16(exp(x[b0+row, p, :])) -> Alds ----
    {
        const float* xrow = x + ((((size_t)(b0 + row)) * NPART + p) * NIN + sub * 16);
        float vals[16];
        #pragma unroll
        for (int j = 0; j < 16; j += 4) {
            float4 v = *(const float4*)(xrow + j);
            vals[j] = v.x; vals[j+1] = v.y; vals[j+2] = v.z; vals[j+3] = v.w;
        }
        ushort8 a0, a1;
        #pragma unroll
        for (int j = 0; j < 8; ++j) a0[j] = f_to_bf16(__expf(vals[j]));
        #pragma unroll
        for (int j = 0; j < 8; ++j) a1[j] = f_to_bf16(__expf(vals[8 + j]));
        unsigned short* dst = Alds + row * LDK + sub * 16;
        *(ushort8*)(dst)     = a0;
        *(ushort8*)(dst + 8) = a1;
    }

    __syncthreads();

    // ---- MFMA: per wave, batch rows m0..m0+15 x all 64 out-nodes ----
    const int wv = t >> 6;       // wave 0..3
    const int l  = t & 63;
    const int ln = l & 15;
    const int q  = l >> 4;       // quad 0..3
    const int m0 = wv * 16;

    // A frag: lane holds A[m = m0+ln][k = q*8 + j]
    const short8 a0 = *(const short8*)(Alds + (m0 + ln) * LDK + q * 8);
    const short8 a1 = *(const short8*)(Alds + (m0 + ln) * LDK + 32 + q * 8);

    floatx4 acc[4];
    #pragma unroll
    for (int ot = 0; ot < 4; ++ot) {
        // B frag: lane holds B[k = q*8+j][n = ot*16+ln] = expw[o = ot*16+ln][i = k]
        const short8 bb0 = *(const short8*)(Wlds + (ot * 16 + ln) * LDK + q * 8);
        const short8 bb1 = *(const short8*)(Wlds + (ot * 16 + ln) * LDK + 32 + q * 8);
        floatx4 c = {0.f, 0.f, 0.f, 0.f};
        c = __builtin_amdgcn_mfma_f32_16x16x32_bf16(a0, bb0, c, 0, 0, 0);
        c = __builtin_amdgcn_mfma_f32_16x16x32_bf16(a1, bb1, c, 0, 0, 0);
        acc[ot] = c;
    }

    // ---- epilogue: out = log(acc) - wlse[o];  D layout: col(n)=ln, row(m)=q*4+r ----
    #pragma unroll
    for (int ot = 0; ot < 4; ++ot) {
        const int o = ot * 16 + ln;
        const float wl = wlse[o];
        #pragma unroll
        for (int r = 0; r < 4; ++r) {
            const int b = b0 + m0 + q * 4 + r;
            out[(((size_t)b) * NPART + p) * NOUT + o] = __logf(acc[ot][r]) - wl;
        }
    }
}

extern "C" void kernel_launch(void* const* d_in, const int* in_sizes, int n_in,
                              void* d_out, int out_size, void* d_ws, size_t ws_size,
                              hipStream_t stream) {
    const float* x = (const float*)d_in[0];   // fp32 [256,128,64]
    const float* w = (const float*)d_in[1];   // fp32 [128,64,64]
    float* out = (float*)d_out;               // fp32 [256,128,64]
    dim3 grid(NPART, NBATCH / 64);
    sumlayer_kernel<<<grid, dim3(256), 0, stream>>>(x, w, out);
}